// Round 6
// baseline (335.525 us; speedup 1.0000x reference)
//
#include <hip/hip_runtime.h>
#include <hip/hip_bf16.h>

#define B 1024

// ---------------- K1: conv 1->4, 3x3, stride2, pad1, ReLU. (B,1,64,64)->(B,4,32,32)
__global__ __launch_bounds__(256) void k_pre1(const float* __restrict__ x,
                                              const float* __restrict__ w,
                                              const float* __restrict__ bias,
                                              float* __restrict__ out) {
    int idx = blockIdx.x * blockDim.x + threadIdx.x;
    if (idx >= B * 32 * 32) return;
    int b = idx >> 10;
    int rem = idx & 1023;
    int oy = rem >> 5, ox = rem & 31;
    const float* xin = x + b * 4096;
    float a0 = bias[0], a1 = bias[1], a2 = bias[2], a3 = bias[3];
#pragma unroll
    for (int ky = 0; ky < 3; ++ky) {
        int iy = 2 * oy - 1 + ky;
        if (iy < 0 || iy >= 64) continue;
#pragma unroll
        for (int kx = 0; kx < 3; ++kx) {
            int ix = 2 * ox - 1 + kx;
            if (ix < 0 || ix >= 64) continue;
            float v = xin[iy * 64 + ix];
            int k = ky * 3 + kx;
            a0 += w[k] * v;
            a1 += w[9 + k] * v;
            a2 += w[18 + k] * v;
            a3 += w[27 + k] * v;
        }
    }
    float* o = out + b * 4096 + oy * 32 + ox;
    o[0]    = fmaxf(a0, 0.f);
    o[1024] = fmaxf(a1, 0.f);
    o[2048] = fmaxf(a2, 0.f);
    o[3072] = fmaxf(a3, 0.f);
}

// ---------------- K2: conv 4->4, 3x3, stride2, pad1, ReLU. (B,4,32,32)->(B,4,16,16)
__global__ __launch_bounds__(256) void k_pre2(const float* __restrict__ in,
                                              const float* __restrict__ w,
                                              const float* __restrict__ bias,
                                              float* __restrict__ out) {
    int idx = blockIdx.x * blockDim.x + threadIdx.x;
    if (idx >= B * 16 * 16) return;
    int b = idx >> 8;
    int rem = idx & 255;
    int oy = rem >> 4, ox = rem & 15;
    const float* xin = in + b * 4096;
    float acc[4] = {bias[0], bias[1], bias[2], bias[3]};
#pragma unroll
    for (int ci = 0; ci < 4; ++ci) {
#pragma unroll
        for (int ky = 0; ky < 3; ++ky) {
            int iy = 2 * oy - 1 + ky;
            if (iy < 0 || iy >= 32) continue;
#pragma unroll
            for (int kx = 0; kx < 3; ++kx) {
                int ix = 2 * ox - 1 + kx;
                if (ix < 0 || ix >= 32) continue;
                float v = xin[ci * 1024 + iy * 32 + ix];
#pragma unroll
                for (int co = 0; co < 4; ++co)
                    acc[co] += w[((co * 4 + ci) * 3 + ky) * 3 + kx] * v;
            }
        }
    }
#pragma unroll
    for (int co = 0; co < 4; ++co)
        out[b * 1024 + co * 256 + oy * 16 + ox] = fmaxf(acc[co], 0.f);
}

// ---------------- K3+K4 fused: pre3 conv (4->4, 3x3, s1, p0) + quanv closed form.
// h2 (B,4,16,16) -> qb (B,16ch,[64-pad]). One thread per (b, c, oh, ow) patch:
// computes the 2x2 h3 patch values directly, then
// z_w = cos(theta_w)cos(x_w) - sin(theta_w)sin(phi_w)sin(x_w); <Z_w> = prod_{v<=w} z_v
__global__ __launch_bounds__(256) void k_pre3_quanv(const float* __restrict__ h2,
                                                    const float* __restrict__ w3,
                                                    const float* __restrict__ b3,
                                                    const float* __restrict__ qw,
                                                    float* __restrict__ q) {
    int idx = blockIdx.x * blockDim.x + threadIdx.x;
    if (idx >= B * 4 * 49) return;
    int b = idx / 196;
    int rem = idx % 196;
    int c = rem / 49;
    int pos = rem % 49;
    int oh = pos / 7, ow = pos % 7;
    const float* xin = h2 + b * 1024;
    float xv[4];
#pragma unroll
    for (int dy = 0; dy < 2; ++dy)
#pragma unroll
        for (int dx = 0; dx < 2; ++dx) {
            int oy = 2 * oh + dy, ox = 2 * ow + dx;
            float acc = b3[c];
#pragma unroll
            for (int ci = 0; ci < 4; ++ci)
#pragma unroll
                for (int ky = 0; ky < 3; ++ky)
#pragma unroll
                    for (int kx = 0; kx < 3; ++kx)
                        acc += w3[((c * 4 + ci) * 3 + ky) * 3 + kx] *
                               xin[ci * 256 + (oy + ky) * 16 + (ox + kx)];
            xv[dy * 2 + dx] = acc;
        }
    float prod = 1.f;
    float* qo = q + b * 1024 + c * 256 + pos;   // padded: 64 floats per channel plane
#pragma unroll
    for (int w = 0; w < 4; ++w) {
        float phi = qw[w * 3 + 0];
        float theta = qw[w * 3 + 1];
        float st, ct, sx, cx;
        __sincosf(theta, &st, &ct);
        float sp = __sinf(phi);
        __sincosf(xv[w], &sx, &cx);
        float z = ct * cx - st * sp * sx;
        prod *= z;
        qo[w * 64] = prod;
    }
}

// ---------------- K4b: weight transposes. conv1_w (32,16,3,3)->tw1[ci][k][co32];
//                                          conv2_w (64,32,3,3)->tw2[ci][k][co64]
__global__ __launch_bounds__(256) void k_transpose_w(const float* __restrict__ cw1,
                                                     const float* __restrict__ cw2,
                                                     float* __restrict__ tw1,
                                                     float* __restrict__ tw2) {
    int i = blockIdx.x * 256 + threadIdx.x;
    if (i < 4608) {
        int co = i & 31; int rest = i >> 5; int k = rest % 9; int ci = rest / 9;
        tw1[i] = cw1[(co * 16 + ci) * 9 + k];
    }
    if (i < 18432) {
        int co = i & 63; int rest = i >> 6; int k = rest % 9; int ci = rest / 9;
        tw2[i] = cw2[(co * 32 + ci) * 9 + k];
    }
}

// --------- register-resident helpers (all indices compile-time after unroll)
__device__ __forceinline__ void load_plane(const float* __restrict__ p, float* dst) {
#pragma unroll
    for (int j = 0; j < 13; ++j) {
        float4 v = reinterpret_cast<const float4*>(p)[j];
        dst[4 * j] = v.x; dst[4 * j + 1] = v.y; dst[4 * j + 2] = v.z; dst[4 * j + 3] = v.w;
    }
}

template <int STRIDE>
__device__ __forceinline__ void load_w9(const float* __restrict__ p, float* w) {
#pragma unroll
    for (int k = 0; k < 9; ++k) w[k] = p[k * STRIDE];
}

__device__ __forceinline__ void conv_acc(const float* pl, const float* w, float* acc) {
#pragma unroll
    for (int oy = 0; oy < 7; ++oy)
#pragma unroll
        for (int ox = 0; ox < 7; ++ox)
#pragma unroll
            for (int ky = 0; ky < 3; ++ky) {
                int iy = oy + ky - 1;
                if (iy < 0 || iy >= 7) continue;
#pragma unroll
                for (int kx = 0; kx < 3; ++kx) {
                    int ix = ox + kx - 1;
                    if (ix < 0 || ix >= 7) continue;
                    acc[oy * 7 + ox] += w[ky * 3 + kx] * pl[iy * 7 + ix];
                }
            }
}

// ---------------- K5: conv1 16->32 + GN(8 groups of 4ch) + ReLU. wave=sample, lane=co.
// in: qb padded [b][16][64]; out: g1 padded [b][32][64]
// __launch_bounds__(64, 1): 1 wave/EU min -> full 512-VGPR budget, no scratch spill
// (R2's plain (64) capped VGPR at 52 and spilled acc/pa/pb -> 76us latency-bound)
__global__ __launch_bounds__(64, 1) void k_conv1_fused(const float* __restrict__ qb,
                                                       const float* __restrict__ tw1,
                                                       const float* __restrict__ bias,
                                                       const float* __restrict__ gw,
                                                       const float* __restrict__ gb,
                                                       float* __restrict__ g1) {
    int b = blockIdx.x;
    int co = threadIdx.x;
    if (co >= 32) return;
    const float* pin = qb + b * 1024;
    float acc[49];
    float bco = bias[co];
#pragma unroll
    for (int p = 0; p < 49; ++p) acc[p] = bco;

    float pa[52], pb[52], wa[9], wb[9];
    load_plane(pin, pa);
    load_w9<32>(tw1 + co, wa);
#pragma unroll
    for (int ci = 0; ci < 16; ci += 2) {
        load_plane(pin + (ci + 1) * 64, pb);
        load_w9<32>(tw1 + (ci + 1) * 288 + co, wb);
        conv_acc(pa, wa, acc);
        if (ci + 2 < 16) {
            load_plane(pin + (ci + 2) * 64, pa);
            load_w9<32>(tw1 + (ci + 2) * 288 + co, wa);
        }
        conv_acc(pb, wb, acc);
    }
    // GroupNorm over 4 adjacent channels x 49 positions (lanes co: group co>>2)
    float sum = 0.f, ssq = 0.f;
#pragma unroll
    for (int p = 0; p < 49; ++p) { sum += acc[p]; ssq += acc[p] * acc[p]; }
    sum += __shfl_xor(sum, 1); ssq += __shfl_xor(ssq, 1);
    sum += __shfl_xor(sum, 2); ssq += __shfl_xor(ssq, 2);
    float mu = sum * (1.f / 196.f);
    float var = ssq * (1.f / 196.f) - mu * mu;
    float rs = rsqrtf(var + 1e-5f);
    float ga = gw[co] * rs;
    float be = gb[co] - mu * ga;
    float* o = g1 + b * 2048 + co * 64;
#pragma unroll
    for (int p = 0; p < 49; ++p) o[p] = fmaxf(acc[p] * ga + be, 0.f);
}

// ---------------- K6: conv2 32->64 + GN(8 groups of 8ch) + ReLU + maxpool2 -> (B,64,3,3)
// in: g1 padded [b][32][64]; out: p2 [b][64][9]
__global__ __launch_bounds__(64, 1) void k_conv2_fused(const float* __restrict__ g1,
                                                       const float* __restrict__ tw2,
                                                       const float* __restrict__ bias,
                                                       const float* __restrict__ gw,
                                                       const float* __restrict__ gb,
                                                       float* __restrict__ out) {
    int b = blockIdx.x;
    int co = threadIdx.x;  // 0..63
    const float* pin = g1 + b * 2048;
    float acc[49];
    float bco = bias[co];
#pragma unroll
    for (int p = 0; p < 49; ++p) acc[p] = bco;

    float pa[52], pb[52], wa[9], wb[9];
    load_plane(pin, pa);
    load_w9<64>(tw2 + co, wa);
#pragma unroll
    for (int ci = 0; ci < 32; ci += 2) {
        load_plane(pin + (ci + 1) * 64, pb);
        load_w9<64>(tw2 + (ci + 1) * 576 + co, wb);
        conv_acc(pa, wa, acc);
        if (ci + 2 < 32) {
            load_plane(pin + (ci + 2) * 64, pa);
            load_w9<64>(tw2 + (ci + 2) * 576 + co, wa);
        }
        conv_acc(pb, wb, acc);
    }
    // GroupNorm over 8 adjacent channels x 49 positions (group co>>3)
    float sum = 0.f, ssq = 0.f;
#pragma unroll
    for (int p = 0; p < 49; ++p) { sum += acc[p]; ssq += acc[p] * acc[p]; }
    sum += __shfl_xor(sum, 1); ssq += __shfl_xor(ssq, 1);
    sum += __shfl_xor(sum, 2); ssq += __shfl_xor(ssq, 2);
    sum += __shfl_xor(sum, 4); ssq += __shfl_xor(ssq, 4);
    float mu = sum * (1.f / 392.f);
    float var = ssq * (1.f / 392.f) - mu * mu;
    float rs = rsqrtf(var + 1e-5f);
    float ga = gw[co] * rs;
    float be = gb[co] - mu * ga;
#pragma unroll
    for (int p = 0; p < 49; ++p) acc[p] = fmaxf(acc[p] * ga + be, 0.f);
    // maxpool 2x2 (rows/cols 0..5) -> 3x3
    float* o = out + b * 576 + co * 9;
#pragma unroll
    for (int py = 0; py < 3; ++py)
#pragma unroll
        for (int px = 0; px < 3; ++px) {
            int p0 = (2 * py) * 7 + 2 * px;
            float m = fmaxf(fmaxf(acc[p0], acc[p0 + 1]), fmaxf(acc[p0 + 7], acc[p0 + 8]));
            o[py * 3 + px] = m;
        }
}

// ---------------- K7: fc1 576->128 + ReLU + fc2 128->10. 8 samples/block, 128 threads.
// Weight rows read once per 8 samples (8x less L2 traffic than 1 sample/block).
__global__ __launch_bounds__(128) void k_fc(const float* __restrict__ p2,
                                            const float* __restrict__ w1,
                                            const float* __restrict__ b1,
                                            const float* __restrict__ w2,
                                            const float* __restrict__ b2,
                                            float* __restrict__ out) {
    __shared__ float s_p[8 * 576];
    __shared__ float s_f[8][132];   // pad 132: avoid 8-way stride-128 bank conflict in fc2
    int b0 = blockIdx.x * 8, tid = threadIdx.x;
    for (int i = tid; i < 8 * 576; i += 128) s_p[i] = p2[b0 * 576 + i];
    __syncthreads();
    {
        float acc[8];
        float bv = b1[tid];
#pragma unroll
        for (int s = 0; s < 8; ++s) acc[s] = bv;
        const float4* wr = reinterpret_cast<const float4*>(w1 + tid * 576);
        const float4* sp = reinterpret_cast<const float4*>(s_p);
        for (int j = 0; j < 144; ++j) {
            float4 a = wr[j];
#pragma unroll
            for (int s = 0; s < 8; ++s) {
                float4 c = sp[s * 144 + j];
                acc[s] += a.x * c.x + a.y * c.y + a.z * c.z + a.w * c.w;
            }
        }
#pragma unroll
        for (int s = 0; s < 8; ++s) s_f[s][tid] = fmaxf(acc[s], 0.f);
    }
    __syncthreads();
    if (tid < 80) {
        int s = tid / 10, o = tid % 10;
        float acc = b2[o];
        const float* wr = w2 + o * 128;
#pragma unroll 8
        for (int j = 0; j < 128; ++j) acc += wr[j] * s_f[s][j];
        out[(b0 + s) * 10 + o] = acc;
    }
}

extern "C" void kernel_launch(void* const* d_in, const int* in_sizes, int n_in,
                              void* d_out, int out_size, void* d_ws, size_t ws_size,
                              hipStream_t stream) {
    const float* x       = (const float*)d_in[0];
    const float* pre_w1  = (const float*)d_in[1];
    const float* pre_b1  = (const float*)d_in[2];
    const float* pre_w2  = (const float*)d_in[3];
    const float* pre_b2  = (const float*)d_in[4];
    const float* pre_w3  = (const float*)d_in[5];
    const float* pre_b3  = (const float*)d_in[6];
    const float* qweights= (const float*)d_in[7];
    const float* conv1_w = (const float*)d_in[8];
    const float* conv1_b = (const float*)d_in[9];
    const float* gn1_w   = (const float*)d_in[10];
    const float* gn1_b   = (const float*)d_in[11];
    const float* conv2_w = (const float*)d_in[12];
    const float* conv2_b = (const float*)d_in[13];
    const float* gn2_w   = (const float*)d_in[14];
    const float* gn2_b   = (const float*)d_in[15];
    const float* fc1_w   = (const float*)d_in[16];
    const float* fc1_b   = (const float*)d_in[17];
    const float* fc2_w   = (const float*)d_in[18];
    const float* fc2_b   = (const float*)d_in[19];
    float* out = (float*)d_out;

    // workspace regions (floats), liveness-based reuse:
    //  A [0, 4194304): h1 (K1-K2); later qb@A (K3q-K5, 1.05M) + g1@A+1048576 (K5-K6, 2.10M)
    //  B [4194304, 5242880): h2 (K2-K3q); later p2 (K6-K7, 0.59M)
    //  D [6045696, +23040): tw1, tw2 (K0-K6)
    float* ws = (float*)d_ws;
    float* h1 = ws;
    float* qb = ws;
    float* g1 = ws + 1048576;
    float* h2 = ws + 4194304;
    float* p2 = ws + 4194304;
    float* tw1 = ws + 6045696;
    float* tw2 = ws + 6045696 + 4608;

    k_transpose_w<<<72, 256, 0, stream>>>(conv1_w, conv2_w, tw1, tw2);
    k_pre1<<<(B * 32 * 32 + 255) / 256, 256, 0, stream>>>(x, pre_w1, pre_b1, h1);
    k_pre2<<<(B * 16 * 16 + 255) / 256, 256, 0, stream>>>(h1, pre_w2, pre_b2, h2);
    k_pre3_quanv<<<(B * 4 * 49 + 255) / 256, 256, 0, stream>>>(h2, pre_w3, pre_b3, qweights, qb);
    k_conv1_fused<<<B, 64, 0, stream>>>(qb, tw1, conv1_b, gn1_w, gn1_b, g1);
    k_conv2_fused<<<B, 64, 0, stream>>>(g1, tw2, conv2_b, gn2_w, gn2_b, p2);
    k_fc<<<(B / 8), 128, 0, stream>>>(p2, fc1_w, fc1_b, fc2_w, fc2_b, out);
}

// Round 7
// 219.458 us; speedup vs baseline: 1.5289x; 1.5289x over previous
//
#include <hip/hip_runtime.h>
#include <hip/hip_bf16.h>

#define B 1024

// ---------------- K1: conv 1->4, 3x3, stride2, pad1, ReLU. (B,1,64,64)->(B,4,32,32)
__global__ __launch_bounds__(256) void k_pre1(const float* __restrict__ x,
                                              const float* __restrict__ w,
                                              const float* __restrict__ bias,
                                              float* __restrict__ out) {
    int idx = blockIdx.x * blockDim.x + threadIdx.x;
    if (idx >= B * 32 * 32) return;
    int b = idx >> 10;
    int rem = idx & 1023;
    int oy = rem >> 5, ox = rem & 31;
    const float* xin = x + b * 4096;
    float a0 = bias[0], a1 = bias[1], a2 = bias[2], a3 = bias[3];
#pragma unroll
    for (int ky = 0; ky < 3; ++ky) {
        int iy = 2 * oy - 1 + ky;
        if (iy < 0 || iy >= 64) continue;
#pragma unroll
        for (int kx = 0; kx < 3; ++kx) {
            int ix = 2 * ox - 1 + kx;
            if (ix < 0 || ix >= 64) continue;
            float v = xin[iy * 64 + ix];
            int k = ky * 3 + kx;
            a0 += w[k] * v;
            a1 += w[9 + k] * v;
            a2 += w[18 + k] * v;
            a3 += w[27 + k] * v;
        }
    }
    float* o = out + b * 4096 + oy * 32 + ox;
    o[0]    = fmaxf(a0, 0.f);
    o[1024] = fmaxf(a1, 0.f);
    o[2048] = fmaxf(a2, 0.f);
    o[3072] = fmaxf(a3, 0.f);
}

// ---------------- K2: conv 4->4, 3x3, stride2, pad1, ReLU. (B,4,32,32)->(B,4,16,16)
__global__ __launch_bounds__(256) void k_pre2(const float* __restrict__ in,
                                              const float* __restrict__ w,
                                              const float* __restrict__ bias,
                                              float* __restrict__ out) {
    int idx = blockIdx.x * blockDim.x + threadIdx.x;
    if (idx >= B * 16 * 16) return;
    int b = idx >> 8;
    int rem = idx & 255;
    int oy = rem >> 4, ox = rem & 15;
    const float* xin = in + b * 4096;
    float acc[4] = {bias[0], bias[1], bias[2], bias[3]};
#pragma unroll
    for (int ci = 0; ci < 4; ++ci) {
#pragma unroll
        for (int ky = 0; ky < 3; ++ky) {
            int iy = 2 * oy - 1 + ky;
            if (iy < 0 || iy >= 32) continue;
#pragma unroll
            for (int kx = 0; kx < 3; ++kx) {
                int ix = 2 * ox - 1 + kx;
                if (ix < 0 || ix >= 32) continue;
                float v = xin[ci * 1024 + iy * 32 + ix];
#pragma unroll
                for (int co = 0; co < 4; ++co)
                    acc[co] += w[((co * 4 + ci) * 3 + ky) * 3 + kx] * v;
            }
        }
    }
#pragma unroll
    for (int co = 0; co < 4; ++co)
        out[b * 1024 + co * 256 + oy * 16 + ox] = fmaxf(acc[co], 0.f);
}

// ---------------- K3+K4 fused: pre3 conv (4->4, 3x3, s1, p0) + quanv closed form.
// h2 (B,4,16,16) -> qb padded planes: per (b,ch): stride 80 floats,
// row r (0..6) at 8*(r+1)+c, zero rows at idx 0-7 and 64-71 (memset provides zeros).
__global__ __launch_bounds__(256) void k_pre3_quanv(const float* __restrict__ h2,
                                                    const float* __restrict__ w3,
                                                    const float* __restrict__ b3,
                                                    const float* __restrict__ qw,
                                                    float* __restrict__ q) {
    int idx = blockIdx.x * blockDim.x + threadIdx.x;
    if (idx >= B * 4 * 49) return;
    int b = idx / 196;
    int rem = idx % 196;
    int c = rem / 49;
    int pos = rem % 49;
    int oh = pos / 7, ow = pos % 7;
    const float* xin = h2 + b * 1024;
    float xv[4];
#pragma unroll
    for (int dy = 0; dy < 2; ++dy)
#pragma unroll
        for (int dx = 0; dx < 2; ++dx) {
            int oy = 2 * oh + dy, ox = 2 * ow + dx;
            float acc = b3[c];
#pragma unroll
            for (int ci = 0; ci < 4; ++ci)
#pragma unroll
                for (int ky = 0; ky < 3; ++ky)
#pragma unroll
                    for (int kx = 0; kx < 3; ++kx)
                        acc += w3[((c * 4 + ci) * 3 + ky) * 3 + kx] *
                               xin[ci * 256 + (oy + ky) * 16 + (ox + kx)];
            xv[dy * 2 + dx] = acc;
        }
    float prod = 1.f;
    // channel = c*4+w, plane stride 80, sample stride 16*80=1280
    float* qo = q + b * 1280 + c * 320 + 8 * (oh + 1) + ow;
#pragma unroll
    for (int w = 0; w < 4; ++w) {
        float phi = qw[w * 3 + 0];
        float theta = qw[w * 3 + 1];
        float st, ct, sx, cx;
        __sincosf(theta, &st, &ct);
        float sp = __sinf(phi);
        __sincosf(xv[w], &sx, &cx);
        float z = ct * cx - st * sp * sx;
        prod *= z;
        qo[w * 80] = prod;
    }
}

// ---------------- K4b: weight transposes. conv1_w (32,16,3,3)->tw1[ci][k][co32];
//                                          conv2_w (64,32,3,3)->tw2[ci][k][co64]
__global__ __launch_bounds__(256) void k_transpose_w(const float* __restrict__ cw1,
                                                     const float* __restrict__ cw2,
                                                     float* __restrict__ tw1,
                                                     float* __restrict__ tw2) {
    int i = blockIdx.x * 256 + threadIdx.x;
    if (i < 4608) {
        int co = i & 31; int rest = i >> 5; int k = rest % 9; int ci = rest / 9;
        tw1[i] = cw1[(co * 16 + ci) * 9 + k];
    }
    if (i < 18432) {
        int co = i & 63; int rest = i >> 6; int k = rest % 9; int ci = rest / 9;
        tw2[i] = cw2[(co * 32 + ci) * 9 + k];
    }
}

// --------- register-resident helpers (all indices compile-time after unroll)
// Load 12 float4 = 6 padded rows of a plane. h=0: plane+0 (rows -1..4);
// h=1: plane+24 (rows 2..7). Reg row r holds global row (r + 3h - 1).
__device__ __forceinline__ void load_plane12(const float* __restrict__ p, float* dst) {
#pragma unroll
    for (int j = 0; j < 12; ++j) {
        float4 v = reinterpret_cast<const float4*>(p)[j];
        dst[4 * j] = v.x; dst[4 * j + 1] = v.y; dst[4 * j + 2] = v.z; dst[4 * j + 3] = v.w;
    }
}

template <int STRIDE>
__device__ __forceinline__ void load_w9(const float* __restrict__ p, float* w) {
#pragma unroll
    for (int k = 0; k < 9; ++k) w[k] = p[k * STRIDE];
}

// Out local row lr (global 3h+lr), input reg row = lr+ky (zero-pad rows absorb
// edges), input col cc = c-1+kx (cc==7 hits zero col pad; only cc<0 skipped).
__device__ __forceinline__ void conv_rows(const float* pr, const float* w9, float* acc) {
#pragma unroll
    for (int lr = 0; lr < 4; ++lr)
#pragma unroll
        for (int c = 0; c < 7; ++c)
#pragma unroll
            for (int ky = 0; ky < 3; ++ky)
#pragma unroll
                for (int kx = 0; kx < 3; ++kx) {
                    int cc = c - 1 + kx;
                    if (cc < 0) continue;
                    acc[lr * 7 + c] += w9[ky * 3 + kx] * pr[(lr + ky) * 8 + cc];
                }
}

// ---------------- K5: conv1 16->32 + GN(8 groups of 4ch) + ReLU.
// wave = sample; lane = co(32) x spatial-half(2). half0 -> out rows 0-3, half1 -> 4-6.
// in: qb padded [b][16][80]; out: g1 padded [b][32][80] (pads pre-zeroed by memset)
__global__ __launch_bounds__(64, 2) void k_conv1_fused(const float* __restrict__ qb,
                                                       const float* __restrict__ tw1,
                                                       const float* __restrict__ bias,
                                                       const float* __restrict__ gw,
                                                       const float* __restrict__ gb,
                                                       float* __restrict__ g1) {
    int b = blockIdx.x;
    int lane = threadIdx.x;
    int co = lane & 31;
    int h = lane >> 5;
    const float* pin = qb + b * 1280 + 24 * h;
    float acc[28];
    float bco = bias[co];
#pragma unroll
    for (int p = 0; p < 28; ++p) acc[p] = bco;

    float pa[48], pb[48], wa[9], wb[9];
    load_plane12(pin, pa);
    load_w9<32>(tw1 + co, wa);
#pragma unroll
    for (int ci = 0; ci < 16; ci += 2) {
        load_plane12(pin + (ci + 1) * 80, pb);
        load_w9<32>(tw1 + (ci + 1) * 288 + co, wb);
        conv_rows(pa, wa, acc);
        if (ci + 2 < 16) {
            load_plane12(pin + (ci + 2) * 80, pa);
            load_w9<32>(tw1 + (ci + 2) * 288 + co, wa);
        }
        conv_rows(pb, wb, acc);
    }
    // GN group = 4 adjacent co x 49 pos. half1's lr0 (row 3) is a duplicate: exclude.
    float sum = 0.f, ssq = 0.f;
#pragma unroll
    for (int lr = 0; lr < 4; ++lr) {
        float rs_ = 0.f, rq_ = 0.f;
#pragma unroll
        for (int c = 0; c < 7; ++c) { float v = acc[lr * 7 + c]; rs_ += v; rq_ += v * v; }
        if (lr > 0 || h == 0) { sum += rs_; ssq += rq_; }
    }
    sum += __shfl_xor(sum, 1);  ssq += __shfl_xor(ssq, 1);
    sum += __shfl_xor(sum, 2);  ssq += __shfl_xor(ssq, 2);
    sum += __shfl_xor(sum, 32); ssq += __shfl_xor(ssq, 32);
    float mu = sum * (1.f / 196.f);
    float var = ssq * (1.f / 196.f) - mu * mu;
    float rs = rsqrtf(var + 1e-5f);
    float ga = gw[co] * rs;
    float be = gb[co] - mu * ga;
    // store rows (half0: 0-3, half1: 4-6) at plane idx 8*(row+1)+c; col 7 stays 0
    float* o = g1 + b * 2560 + co * 80;
#pragma unroll
    for (int lr = 0; lr < 4; ++lr) {
        if (h == 1 && lr == 0) continue;
        int row = lr + 3 * h;
        float r0 = fmaxf(acc[lr * 7 + 0] * ga + be, 0.f);
        float r1 = fmaxf(acc[lr * 7 + 1] * ga + be, 0.f);
        float r2 = fmaxf(acc[lr * 7 + 2] * ga + be, 0.f);
        float r3 = fmaxf(acc[lr * 7 + 3] * ga + be, 0.f);
        float r4 = fmaxf(acc[lr * 7 + 4] * ga + be, 0.f);
        float r5 = fmaxf(acc[lr * 7 + 5] * ga + be, 0.f);
        float r6 = fmaxf(acc[lr * 7 + 6] * ga + be, 0.f);
        float* rowp = o + 8 * (row + 1);
        *reinterpret_cast<float4*>(rowp) = make_float4(r0, r1, r2, r3);
        *reinterpret_cast<float2*>(rowp + 4) = make_float2(r4, r5);
        rowp[6] = r6;
    }
}

// ---------------- K6: conv2 32->64 + GN(8 groups of 8ch) + ReLU + maxpool2 -> (B,64,3,3)
// 2 waves/sample: wave k covers co 32k..32k+31. lane = co_local(32) x half(2).
// in: g1 padded [b][32][80]; out: p2 [b][64][9]
__global__ __launch_bounds__(64, 2) void k_conv2_fused(const float* __restrict__ g1,
                                                       const float* __restrict__ tw2,
                                                       const float* __restrict__ bias,
                                                       const float* __restrict__ gw,
                                                       const float* __restrict__ gb,
                                                       float* __restrict__ out) {
    int b = blockIdx.x >> 1;
    int wk = blockIdx.x & 1;
    int lane = threadIdx.x;
    int co = wk * 32 + (lane & 31);
    int h = lane >> 5;
    const float* pin = g1 + b * 2560 + 24 * h;
    float acc[28];
    float bco = bias[co];
#pragma unroll
    for (int p = 0; p < 28; ++p) acc[p] = bco;

    float pa[48], pb[48], wa[9], wb[9];
    load_plane12(pin, pa);
    load_w9<64>(tw2 + co, wa);
#pragma unroll
    for (int ci = 0; ci < 32; ci += 2) {
        load_plane12(pin + (ci + 1) * 80, pb);
        load_w9<64>(tw2 + (ci + 1) * 576 + co, wb);
        conv_rows(pa, wa, acc);
        if (ci + 2 < 32) {
            load_plane12(pin + (ci + 2) * 80, pa);
            load_w9<64>(tw2 + (ci + 2) * 576 + co, wa);
        }
        conv_rows(pb, wb, acc);
    }
    // GN group = 8 adjacent co x 49 pos (groups 4wk..4wk+3, fully in-wave)
    float sum = 0.f, ssq = 0.f;
#pragma unroll
    for (int lr = 0; lr < 4; ++lr) {
        float rs_ = 0.f, rq_ = 0.f;
#pragma unroll
        for (int c = 0; c < 7; ++c) { float v = acc[lr * 7 + c]; rs_ += v; rq_ += v * v; }
        if (lr > 0 || h == 0) { sum += rs_; ssq += rq_; }
    }
    sum += __shfl_xor(sum, 1);  ssq += __shfl_xor(ssq, 1);
    sum += __shfl_xor(sum, 2);  ssq += __shfl_xor(ssq, 2);
    sum += __shfl_xor(sum, 4);  ssq += __shfl_xor(ssq, 4);
    sum += __shfl_xor(sum, 32); ssq += __shfl_xor(ssq, 32);
    float mu = sum * (1.f / 392.f);
    float var = ssq * (1.f / 392.f) - mu * mu;
    float rs = rsqrtf(var + 1e-5f);
    float ga = gw[co] * rs;
    float be = gb[co] - mu * ga;
#pragma unroll
    for (int p = 0; p < 28; ++p) acc[p] = fmaxf(acc[p] * ga + be, 0.f);
    // maxpool 2x2 on rows/cols 0..5. half0: py 0,1 (rows 0-3 = lr 0-3); half1: py 2 (rows 4,5 = lr 1,2)
    float* o = out + b * 576 + co * 9;
    if (h == 0) {
#pragma unroll
        for (int py = 0; py < 2; ++py)
#pragma unroll
            for (int px = 0; px < 3; ++px) {
                int p0 = (2 * py) * 7 + 2 * px;
                float m = fmaxf(fmaxf(acc[p0], acc[p0 + 1]), fmaxf(acc[p0 + 7], acc[p0 + 8]));
                o[py * 3 + px] = m;
            }
    } else {
#pragma unroll
        for (int px = 0; px < 3; ++px) {
            int p0 = 7 + 2 * px;   // lr 1 = global row 4
            float m = fmaxf(fmaxf(acc[p0], acc[p0 + 1]), fmaxf(acc[p0 + 7], acc[p0 + 8]));
            o[6 + px] = m;
        }
    }
}

// ---------------- K7: fc1 576->128 + ReLU + fc2 128->10. 8 samples/block, 128 threads.
__global__ __launch_bounds__(128) void k_fc(const float* __restrict__ p2,
                                            const float* __restrict__ w1,
                                            const float* __restrict__ b1,
                                            const float* __restrict__ w2,
                                            const float* __restrict__ b2,
                                            float* __restrict__ out) {
    __shared__ float s_p[8 * 576];
    __shared__ float s_f[8][132];   // pad 132: avoid 8-way stride-128 bank conflict in fc2
    int b0 = blockIdx.x * 8, tid = threadIdx.x;
    for (int i = tid; i < 8 * 576; i += 128) s_p[i] = p2[b0 * 576 + i];
    __syncthreads();
    {
        float acc[8];
        float bv = b1[tid];
#pragma unroll
        for (int s = 0; s < 8; ++s) acc[s] = bv;
        const float4* wr = reinterpret_cast<const float4*>(w1 + tid * 576);
        const float4* sp = reinterpret_cast<const float4*>(s_p);
        for (int j = 0; j < 144; ++j) {
            float4 a = wr[j];
#pragma unroll
            for (int s = 0; s < 8; ++s) {
                float4 c = sp[s * 144 + j];
                acc[s] += a.x * c.x + a.y * c.y + a.z * c.z + a.w * c.w;
            }
        }
#pragma unroll
        for (int s = 0; s < 8; ++s) s_f[s][tid] = fmaxf(acc[s], 0.f);
    }
    __syncthreads();
    if (tid < 80) {
        int s = tid / 10, o = tid % 10;
        float acc = b2[o];
        const float* wr = w2 + o * 128;
#pragma unroll 8
        for (int j = 0; j < 128; ++j) acc += wr[j] * s_f[s][j];
        out[(b0 + s) * 10 + o] = acc;
    }
}

extern "C" void kernel_launch(void* const* d_in, const int* in_sizes, int n_in,
                              void* d_out, int out_size, void* d_ws, size_t ws_size,
                              hipStream_t stream) {
    const float* x       = (const float*)d_in[0];
    const float* pre_w1  = (const float*)d_in[1];
    const float* pre_b1  = (const float*)d_in[2];
    const float* pre_w2  = (const float*)d_in[3];
    const float* pre_b2  = (const float*)d_in[4];
    const float* pre_w3  = (const float*)d_in[5];
    const float* pre_b3  = (const float*)d_in[6];
    const float* qweights= (const float*)d_in[7];
    const float* conv1_w = (const float*)d_in[8];
    const float* conv1_b = (const float*)d_in[9];
    const float* gn1_w   = (const float*)d_in[10];
    const float* gn1_b   = (const float*)d_in[11];
    const float* conv2_w = (const float*)d_in[12];
    const float* conv2_b = (const float*)d_in[13];
    const float* gn2_w   = (const float*)d_in[14];
    const float* gn2_b   = (const float*)d_in[15];
    const float* fc1_w   = (const float*)d_in[16];
    const float* fc1_b   = (const float*)d_in[17];
    const float* fc2_w   = (const float*)d_in[18];
    const float* fc2_b   = (const float*)d_in[19];
    float* out = (float*)d_out;

    // workspace (floats), liveness-based reuse:
    //  h1 [0, 4194304)            : K1->K2
    //  qb [0, 1310720)            : K3q->K5 (after h1 dead; memset-zeroed pads)
    //  g1 [1310720, 3932160)      : K5->K6 (memset-zeroed pads)
    //  h2 [4194304, 5242880)      : K2->K3q
    //  p2 [4194304, 4784128)      : K6->K7 (reuses h2 region)
    //  tw [6045696, +23040)       : K0->K6
    float* ws = (float*)d_ws;
    float* h1 = ws;
    float* qb = ws;
    float* g1 = ws + 1310720;
    float* h2 = ws + 4194304;
    float* p2 = ws + 4194304;
    float* tw1 = ws + 6045696;
    float* tw2 = ws + 6045696 + 4608;

    k_transpose_w<<<72, 256, 0, stream>>>(conv1_w, conv2_w, tw1, tw2);
    k_pre1<<<(B * 32 * 32 + 255) / 256, 256, 0, stream>>>(x, pre_w1, pre_b1, h1);
    k_pre2<<<(B * 16 * 16 + 255) / 256, 256, 0, stream>>>(h1, pre_w2, pre_b2, h2);
    // zero qb+g1 (pads must be 0; h1 is dead after k_pre2)
    hipMemsetAsync(ws, 0, 3932160 * sizeof(float), stream);
    k_pre3_quanv<<<(B * 4 * 49 + 255) / 256, 256, 0, stream>>>(h2, pre_w3, pre_b3, qweights, qb);
    k_conv1_fused<<<B, 64, 0, stream>>>(qb, tw1, conv1_b, gn1_w, gn1_b, g1);
    k_conv2_fused<<<2 * B, 64, 0, stream>>>(g1, tw2, conv2_b, gn2_w, gn2_b, p2);
    k_fc<<<(B / 8), 128, 0, stream>>>(p2, fc1_w, fc1_b, fc2_w, fc2_b, out);
}

// Round 11
// 215.286 us; speedup vs baseline: 1.5585x; 1.0194x over previous
//
#include <hip/hip_runtime.h>
#include <hip/hip_bf16.h>

#define B 1024

// ---------------- K1: conv 1->4, 3x3, stride2, pad1, ReLU. (B,1,64,64)->(B,4,32,32)
// Tail blocks (idx >= B*32*32) also do the conv1/conv2 weight transposes.
__global__ __launch_bounds__(256) void k_pre1(const float* __restrict__ x,
                                              const float* __restrict__ w,
                                              const float* __restrict__ bias,
                                              float* __restrict__ out,
                                              const float* __restrict__ cw1,
                                              const float* __restrict__ cw2,
                                              float* __restrict__ tw1,
                                              float* __restrict__ tw2) {
    int idx = blockIdx.x * blockDim.x + threadIdx.x;
    if (idx >= B * 32 * 32) {
        int i = idx - B * 32 * 32;
        if (i < 4608) {
            int co = i & 31; int rest = i >> 5; int k = rest % 9; int ci = rest / 9;
            tw1[i] = cw1[(co * 16 + ci) * 9 + k];
        }
        if (i < 18432) {
            int co = i & 63; int rest = i >> 6; int k = rest % 9; int ci = rest / 9;
            tw2[i] = cw2[(co * 32 + ci) * 9 + k];
        }
        return;
    }
    int b = idx >> 10;
    int rem = idx & 1023;
    int oy = rem >> 5, ox = rem & 31;
    const float* xin = x + b * 4096;
    float a0 = bias[0], a1 = bias[1], a2 = bias[2], a3 = bias[3];
#pragma unroll
    for (int ky = 0; ky < 3; ++ky) {
        int iy = 2 * oy - 1 + ky;
        if (iy < 0 || iy >= 64) continue;
#pragma unroll
        for (int kx = 0; kx < 3; ++kx) {
            int ix = 2 * ox - 1 + kx;
            if (ix < 0 || ix >= 64) continue;
            float v = xin[iy * 64 + ix];
            int k = ky * 3 + kx;
            a0 += w[k] * v;
            a1 += w[9 + k] * v;
            a2 += w[18 + k] * v;
            a3 += w[27 + k] * v;
        }
    }
    float* o = out + b * 4096 + oy * 32 + ox;
    o[0]    = fmaxf(a0, 0.f);
    o[1024] = fmaxf(a1, 0.f);
    o[2048] = fmaxf(a2, 0.f);
    o[3072] = fmaxf(a3, 0.f);
}

// ---------------- K2: conv 4->4, 3x3, stride2, pad1, ReLU. (B,4,32,32)->(B,4,16,16)
__global__ __launch_bounds__(256) void k_pre2(const float* __restrict__ in,
                                              const float* __restrict__ w,
                                              const float* __restrict__ bias,
                                              float* __restrict__ out) {
    int idx = blockIdx.x * blockDim.x + threadIdx.x;
    if (idx >= B * 16 * 16) return;
    int b = idx >> 8;
    int rem = idx & 255;
    int oy = rem >> 4, ox = rem & 15;
    const float* xin = in + b * 4096;
    float acc[4] = {bias[0], bias[1], bias[2], bias[3]};
#pragma unroll
    for (int ci = 0; ci < 4; ++ci) {
#pragma unroll
        for (int ky = 0; ky < 3; ++ky) {
            int iy = 2 * oy - 1 + ky;
            if (iy < 0 || iy >= 32) continue;
#pragma unroll
            for (int kx = 0; kx < 3; ++kx) {
                int ix = 2 * ox - 1 + kx;
                if (ix < 0 || ix >= 32) continue;
                float v = xin[ci * 1024 + iy * 32 + ix];
#pragma unroll
                for (int co = 0; co < 4; ++co)
                    acc[co] += w[((co * 4 + ci) * 3 + ky) * 3 + kx] * v;
            }
        }
    }
#pragma unroll
    for (int co = 0; co < 4; ++co)
        out[b * 1024 + co * 256 + oy * 16 + ox] = fmaxf(acc[co], 0.f);
}

// ---------------- K3+K4 fused: pre3 conv (4->4, 3x3, s1, p0) + quanv closed form.
// h2 (B,4,16,16) -> qb padded planes: per (b,ch): stride 80 floats,
// row r (0..6) at 8*(r+1)+c. Pads are zero via the preceding memset.
__global__ __launch_bounds__(256) void k_pre3_quanv(const float* __restrict__ h2,
                                                    const float* __restrict__ w3,
                                                    const float* __restrict__ b3,
                                                    const float* __restrict__ qw,
                                                    float* __restrict__ q) {
    int idx = blockIdx.x * blockDim.x + threadIdx.x;
    if (idx >= B * 4 * 49) return;
    int b = idx / 196;
    int rem = idx % 196;
    int c = rem / 49;
    int pos = rem % 49;
    int oh = pos / 7, ow = pos % 7;
    const float* xin = h2 + b * 1024;
    float xv[4];
#pragma unroll
    for (int dy = 0; dy < 2; ++dy)
#pragma unroll
        for (int dx = 0; dx < 2; ++dx) {
            int oy = 2 * oh + dy, ox = 2 * ow + dx;
            float acc = b3[c];
#pragma unroll
            for (int ci = 0; ci < 4; ++ci)
#pragma unroll
                for (int ky = 0; ky < 3; ++ky)
#pragma unroll
                    for (int kx = 0; kx < 3; ++kx)
                        acc += w3[((c * 4 + ci) * 3 + ky) * 3 + kx] *
                               xin[ci * 256 + (oy + ky) * 16 + (ox + kx)];
            xv[dy * 2 + dx] = acc;
        }
    float prod = 1.f;
    // channel = c*4+w, plane stride 80, sample stride 16*80=1280
    float* qo = q + b * 1280 + c * 320 + 8 * (oh + 1) + ow;
#pragma unroll
    for (int w = 0; w < 4; ++w) {
        float phi = qw[w * 3 + 0];
        float theta = qw[w * 3 + 1];
        float st, ct, sx, cx;
        __sincosf(theta, &st, &ct);
        float sp = __sinf(phi);
        __sincosf(xv[w], &sx, &cx);
        float z = ct * cx - st * sp * sx;
        prod *= z;
        qo[w * 80] = prod;
    }
}

// --------- register-resident helpers (all indices compile-time after unroll)
// Load 12 float4 = 6 padded rows of a plane. h=0: plane+0 (rows -1..4);
// h=1: plane+24 (rows 2..7). Reg row r holds global row (r + 3h - 1).
__device__ __forceinline__ void load_plane12(const float* __restrict__ p, float* dst) {
#pragma unroll
    for (int j = 0; j < 12; ++j) {
        float4 v = reinterpret_cast<const float4*>(p)[j];
        dst[4 * j] = v.x; dst[4 * j + 1] = v.y; dst[4 * j + 2] = v.z; dst[4 * j + 3] = v.w;
    }
}

template <int STRIDE>
__device__ __forceinline__ void load_w9(const float* __restrict__ p, float* w) {
#pragma unroll
    for (int k = 0; k < 9; ++k) w[k] = p[k * STRIDE];
}

// Out local row lr (global 3h+lr), input reg row = lr+ky (zero-pad rows absorb
// edges), input col cc = c-1+kx (cc==7 hits zero col pad; only cc<0 skipped).
__device__ __forceinline__ void conv_rows(const float* pr, const float* w9, float* acc) {
#pragma unroll
    for (int lr = 0; lr < 4; ++lr)
#pragma unroll
        for (int c = 0; c < 7; ++c)
#pragma unroll
            for (int ky = 0; ky < 3; ++ky)
#pragma unroll
                for (int kx = 0; kx < 3; ++kx) {
                    int cc = c - 1 + kx;
                    if (cc < 0) continue;
                    acc[lr * 7 + c] += w9[ky * 3 + kx] * pr[(lr + ky) * 8 + cc];
                }
}

// ---------------- K5: conv1 16->32 + GN(8 groups of 4ch) + ReLU.
// wave = sample; lane = co(32) x spatial-half(2). half0 -> out rows 0-3, half1 -> 4-6.
// in: qb padded [b][16][80]; out: g1 padded [b][32][80] (pads pre-zeroed by memset)
__global__ __launch_bounds__(64, 2) void k_conv1_fused(const float* __restrict__ qb,
                                                       const float* __restrict__ tw1,
                                                       const float* __restrict__ bias,
                                                       const float* __restrict__ gw,
                                                       const float* __restrict__ gb,
                                                       float* __restrict__ g1) {
    int b = blockIdx.x;
    int lane = threadIdx.x;
    int co = lane & 31;
    int h = lane >> 5;
    const float* pin = qb + b * 1280 + 24 * h;
    float acc[28];
    float bco = bias[co];
#pragma unroll
    for (int p = 0; p < 28; ++p) acc[p] = bco;

    float pa[48], pb[48], wa[9], wb[9];
    load_plane12(pin, pa);
    load_w9<32>(tw1 + co, wa);
#pragma unroll
    for (int ci = 0; ci < 16; ci += 2) {
        load_plane12(pin + (ci + 1) * 80, pb);
        load_w9<32>(tw1 + (ci + 1) * 288 + co, wb);
        conv_rows(pa, wa, acc);
        if (ci + 2 < 16) {
            load_plane12(pin + (ci + 2) * 80, pa);
            load_w9<32>(tw1 + (ci + 2) * 288 + co, wa);
        }
        conv_rows(pb, wb, acc);
    }
    // GN group = 4 adjacent co x 49 pos. half1's lr0 (row 3) is a duplicate: exclude.
    float sum = 0.f, ssq = 0.f;
#pragma unroll
    for (int lr = 0; lr < 4; ++lr) {
        float rs_ = 0.f, rq_ = 0.f;
#pragma unroll
        for (int c = 0; c < 7; ++c) { float v = acc[lr * 7 + c]; rs_ += v; rq_ += v * v; }
        if (lr > 0 || h == 0) { sum += rs_; ssq += rq_; }
    }
    sum += __shfl_xor(sum, 1);  ssq += __shfl_xor(ssq, 1);
    sum += __shfl_xor(sum, 2);  ssq += __shfl_xor(ssq, 2);
    sum += __shfl_xor(sum, 32); ssq += __shfl_xor(ssq, 32);
    float mu = sum * (1.f / 196.f);
    float var = ssq * (1.f / 196.f) - mu * mu;
    float rs = rsqrtf(var + 1e-5f);
    float ga = gw[co] * rs;
    float be = gb[co] - mu * ga;
    // store rows (half0: 0-3, half1: 4-6) at plane idx 8*(row+1)+c; col 7 stays 0
    float* o = g1 + b * 2560 + co * 80;
#pragma unroll
    for (int lr = 0; lr < 4; ++lr) {
        if (h == 1 && lr == 0) continue;
        int row = lr + 3 * h;
        float r0 = fmaxf(acc[lr * 7 + 0] * ga + be, 0.f);
        float r1 = fmaxf(acc[lr * 7 + 1] * ga + be, 0.f);
        float r2 = fmaxf(acc[lr * 7 + 2] * ga + be, 0.f);
        float r3 = fmaxf(acc[lr * 7 + 3] * ga + be, 0.f);
        float r4 = fmaxf(acc[lr * 7 + 4] * ga + be, 0.f);
        float r5 = fmaxf(acc[lr * 7 + 5] * ga + be, 0.f);
        float r6 = fmaxf(acc[lr * 7 + 6] * ga + be, 0.f);
        float* rowp = o + 8 * (row + 1);
        *reinterpret_cast<float4*>(rowp) = make_float4(r0, r1, r2, r3);
        *reinterpret_cast<float2*>(rowp + 4) = make_float2(r4, r5);
        rowp[6] = r6;
    }
}

// ---------------- K6: conv2 32->64 + GN(8 groups of 8ch) + ReLU + maxpool2 -> (B,64,3,3)
// 2 waves/sample: wave k covers co 32k..32k+31. lane = co_local(32) x half(2).
// in: g1 padded [b][32][80]; out: p2 [b][64][9]
__global__ __launch_bounds__(64, 2) void k_conv2_fused(const float* __restrict__ g1,
                                                       const float* __restrict__ tw2,
                                                       const float* __restrict__ bias,
                                                       const float* __restrict__ gw,
                                                       const float* __restrict__ gb,
                                                       float* __restrict__ out) {
    int b = blockIdx.x >> 1;
    int wk = blockIdx.x & 1;
    int lane = threadIdx.x;
    int co = wk * 32 + (lane & 31);
    int h = lane >> 5;
    const float* pin = g1 + b * 2560 + 24 * h;
    float acc[28];
    float bco = bias[co];
#pragma unroll
    for (int p = 0; p < 28; ++p) acc[p] = bco;

    float pa[48], pb[48], wa[9], wb[9];
    load_plane12(pin, pa);
    load_w9<64>(tw2 + co, wa);
#pragma unroll
    for (int ci = 0; ci < 32; ci += 2) {
        load_plane12(pin + (ci + 1) * 80, pb);
        load_w9<64>(tw2 + (ci + 1) * 576 + co, wb);
        conv_rows(pa, wa, acc);
        if (ci + 2 < 32) {
            load_plane12(pin + (ci + 2) * 80, pa);
            load_w9<64>(tw2 + (ci + 2) * 576 + co, wa);
        }
        conv_rows(pb, wb, acc);
    }
    // GN group = 8 adjacent co x 49 pos (groups 4wk..4wk+3, fully in-wave)
    float sum = 0.f, ssq = 0.f;
#pragma unroll
    for (int lr = 0; lr < 4; ++lr) {
        float rs_ = 0.f, rq_ = 0.f;
#pragma unroll
        for (int c = 0; c < 7; ++c) { float v = acc[lr * 7 + c]; rs_ += v; rq_ += v * v; }
        if (lr > 0 || h == 0) { sum += rs_; ssq += rq_; }
    }
    sum += __shfl_xor(sum, 1);  ssq += __shfl_xor(ssq, 1);
    sum += __shfl_xor(sum, 2);  ssq += __shfl_xor(ssq, 2);
    sum += __shfl_xor(sum, 4);  ssq += __shfl_xor(ssq, 4);
    sum += __shfl_xor(sum, 32); ssq += __shfl_xor(ssq, 32);
    float mu = sum * (1.f / 392.f);
    float var = ssq * (1.f / 392.f) - mu * mu;
    float rs = rsqrtf(var + 1e-5f);
    float ga = gw[co] * rs;
    float be = gb[co] - mu * ga;
#pragma unroll
    for (int p = 0; p < 28; ++p) acc[p] = fmaxf(acc[p] * ga + be, 0.f);
    // maxpool 2x2 on rows/cols 0..5. half0: py 0,1 (rows 0-3 = lr 0-3); half1: py 2 (rows 4,5 = lr 1,2)
    float* o = out + b * 576 + co * 9;
    if (h == 0) {
#pragma unroll
        for (int py = 0; py < 2; ++py)
#pragma unroll
            for (int px = 0; px < 3; ++px) {
                int p0 = (2 * py) * 7 + 2 * px;
                float m = fmaxf(fmaxf(acc[p0], acc[p0 + 1]), fmaxf(acc[p0 + 7], acc[p0 + 8]));
                o[py * 3 + px] = m;
            }
    } else {
#pragma unroll
        for (int px = 0; px < 3; ++px) {
            int p0 = 7 + 2 * px;   // lr 1 = global row 4
            float m = fmaxf(fmaxf(acc[p0], acc[p0 + 1]), fmaxf(acc[p0 + 7], acc[p0 + 8]));
            o[6 + px] = m;
        }
    }
}

// ---------------- K7: fc1 576->128 + ReLU + fc2 128->10. 8 samples/block, 128 threads.
__global__ __launch_bounds__(128) void k_fc(const float* __restrict__ p2,
                                            const float* __restrict__ w1,
                                            const float* __restrict__ b1,
                                            const float* __restrict__ w2,
                                            const float* __restrict__ b2,
                                            float* __restrict__ out) {
    __shared__ float s_p[8 * 576];
    __shared__ float s_f[8][132];   // pad 132: avoid 8-way stride-128 bank conflict in fc2
    int b0 = blockIdx.x * 8, tid = threadIdx.x;
    for (int i = tid; i < 8 * 576; i += 128) s_p[i] = p2[b0 * 576 + i];
    __syncthreads();
    {
        float acc[8];
        float bv = b1[tid];
#pragma unroll
        for (int s = 0; s < 8; ++s) acc[s] = bv;
        const float4* wr = reinterpret_cast<const float4*>(w1 + tid * 576);
        const float4* sp = reinterpret_cast<const float4*>(s_p);
        for (int j = 0; j < 144; ++j) {
            float4 a = wr[j];
#pragma unroll
            for (int s = 0; s < 8; ++s) {
                float4 c = sp[s * 144 + j];
                acc[s] += a.x * c.x + a.y * c.y + a.z * c.z + a.w * c.w;
            }
        }
#pragma unroll
        for (int s = 0; s < 8; ++s) s_f[s][tid] = fmaxf(acc[s], 0.f);
    }
    __syncthreads();
    if (tid < 80) {
        int s = tid / 10, o = tid % 10;
        float acc = b2[o];
        const float* wr = w2 + o * 128;
#pragma unroll 8
        for (int j = 0; j < 128; ++j) acc += wr[j] * s_f[s][j];
        out[(b0 + s) * 10 + o] = acc;
    }
}

extern "C" void kernel_launch(void* const* d_in, const int* in_sizes, int n_in,
                              void* d_out, int out_size, void* d_ws, size_t ws_size,
                              hipStream_t stream) {
    const float* x       = (const float*)d_in[0];
    const float* pre_w1  = (const float*)d_in[1];
    const float* pre_b1  = (const float*)d_in[2];
    const float* pre_w2  = (const float*)d_in[3];
    const float* pre_b2  = (const float*)d_in[4];
    const float* pre_w3  = (const float*)d_in[5];
    const float* pre_b3  = (const float*)d_in[6];
    const float* qweights= (const float*)d_in[7];
    const float* conv1_w = (const float*)d_in[8];
    const float* conv1_b = (const float*)d_in[9];
    const float* gn1_w   = (const float*)d_in[10];
    const float* gn1_b   = (const float*)d_in[11];
    const float* conv2_w = (const float*)d_in[12];
    const float* conv2_b = (const float*)d_in[13];
    const float* gn2_w   = (const float*)d_in[14];
    const float* gn2_b   = (const float*)d_in[15];
    const float* fc1_w   = (const float*)d_in[16];
    const float* fc1_b   = (const float*)d_in[17];
    const float* fc2_w   = (const float*)d_in[18];
    const float* fc2_b   = (const float*)d_in[19];
    float* out = (float*)d_out;

    // workspace (floats), liveness-based reuse (R7-proven layout):
    //  h1 [0, 4194304)            : K1->K2
    //  qb [0, 1310720)            : K3q->K5 (after h1 dead; memset-zeroed pads)
    //  g1 [1310720, 3932160)      : K5->K6 (memset-zeroed pads)
    //  h2 [4194304, 5242880)      : K2->K3q
    //  p2 [4194304, 4784128)      : K6->K7 (reuses h2 region)
    //  tw [6045696, +23040)       : K1->K6
    float* ws = (float*)d_ws;
    float* h1 = ws;
    float* qb = ws;
    float* g1 = ws + 1310720;
    float* h2 = ws + 4194304;
    float* p2 = ws + 4194304;
    float* tw1 = ws + 6045696;
    float* tw2 = ws + 6045696 + 4608;

    k_pre1<<<4168, 256, 0, stream>>>(x, pre_w1, pre_b1, h1, conv1_w, conv2_w, tw1, tw2);
    k_pre2<<<(B * 16 * 16 + 255) / 256, 256, 0, stream>>>(h1, pre_w2, pre_b2, h2);
    // zero qb+g1 (pads must be 0; h1 is dead after k_pre2)
    hipMemsetAsync(ws, 0, 3932160 * sizeof(float), stream);
    k_pre3_quanv<<<(B * 4 * 49 + 255) / 256, 256, 0, stream>>>(h2, pre_w3, pre_b3, qweights, qb);
    k_conv1_fused<<<B, 64, 0, stream>>>(qb, tw1, conv1_b, gn1_w, gn1_b, g1);
    k_conv2_fused<<<2 * B, 64, 0, stream>>>(g1, tw2, conv2_b, gn2_w, gn2_b, p2);
    k_fc<<<(B / 8), 128, 0, stream>>>(p2, fc1_w, fc1_b, fc2_w, fc2_b, out);
}

// Round 15
// 199.788 us; speedup vs baseline: 1.6794x; 1.0776x over previous
//
#include <hip/hip_runtime.h>
#include <hip/hip_bf16.h>

#define B 1024

// ---------------- K1: conv 1->4, 3x3, stride2, pad1, ReLU. (B,1,64,64)->(B,4,32,32)
// Tail blocks (idx >= B*32*32) also do the conv1/conv2 weight transposes.
__global__ __launch_bounds__(256) void k_pre1(const float* __restrict__ x,
                                              const float* __restrict__ w,
                                              const float* __restrict__ bias,
                                              float* __restrict__ out,
                                              const float* __restrict__ cw1,
                                              const float* __restrict__ cw2,
                                              float* __restrict__ tw1,
                                              float* __restrict__ tw2) {
    int idx = blockIdx.x * blockDim.x + threadIdx.x;
    if (idx >= B * 32 * 32) {
        int i = idx - B * 32 * 32;
        if (i < 4608) {
            int co = i & 31; int rest = i >> 5; int k = rest % 9; int ci = rest / 9;
            tw1[i] = cw1[(co * 16 + ci) * 9 + k];
        }
        if (i < 18432) {
            int co = i & 63; int rest = i >> 6; int k = rest % 9; int ci = rest / 9;
            tw2[i] = cw2[(co * 32 + ci) * 9 + k];
        }
        return;
    }
    int b = idx >> 10;
    int rem = idx & 1023;
    int oy = rem >> 5, ox = rem & 31;
    const float* xin = x + b * 4096;
    float a0 = bias[0], a1 = bias[1], a2 = bias[2], a3 = bias[3];
#pragma unroll
    for (int ky = 0; ky < 3; ++ky) {
        int iy = 2 * oy - 1 + ky;
        if (iy < 0 || iy >= 64) continue;
#pragma unroll
        for (int kx = 0; kx < 3; ++kx) {
            int ix = 2 * ox - 1 + kx;
            if (ix < 0 || ix >= 64) continue;
            float v = xin[iy * 64 + ix];
            int k = ky * 3 + kx;
            a0 += w[k] * v;
            a1 += w[9 + k] * v;
            a2 += w[18 + k] * v;
            a3 += w[27 + k] * v;
        }
    }
    float* o = out + b * 4096 + oy * 32 + ox;
    o[0]    = fmaxf(a0, 0.f);
    o[1024] = fmaxf(a1, 0.f);
    o[2048] = fmaxf(a2, 0.f);
    o[3072] = fmaxf(a3, 0.f);
}

// ---------------- K2: conv 4->4, 3x3, stride2, pad1, ReLU. (B,4,32,32)->(B,4,16,16)
__global__ __launch_bounds__(256) void k_pre2(const float* __restrict__ in,
                                              const float* __restrict__ w,
                                              const float* __restrict__ bias,
                                              float* __restrict__ out) {
    int idx = blockIdx.x * blockDim.x + threadIdx.x;
    if (idx >= B * 16 * 16) return;
    int b = idx >> 8;
    int rem = idx & 255;
    int oy = rem >> 4, ox = rem & 15;
    const float* xin = in + b * 4096;
    float acc[4] = {bias[0], bias[1], bias[2], bias[3]};
#pragma unroll
    for (int ci = 0; ci < 4; ++ci) {
#pragma unroll
        for (int ky = 0; ky < 3; ++ky) {
            int iy = 2 * oy - 1 + ky;
            if (iy < 0 || iy >= 32) continue;
#pragma unroll
            for (int kx = 0; kx < 3; ++kx) {
                int ix = 2 * ox - 1 + kx;
                if (ix < 0 || ix >= 32) continue;
                float v = xin[ci * 1024 + iy * 32 + ix];
#pragma unroll
                for (int co = 0; co < 4; ++co)
                    acc[co] += w[((co * 4 + ci) * 3 + ky) * 3 + kx] * v;
            }
        }
    }
#pragma unroll
    for (int co = 0; co < 4; ++co)
        out[b * 1024 + co * 256 + oy * 16 + ox] = fmaxf(acc[co], 0.f);
}

// ---------------- K3+K4 fused: pre3 conv (4->4, 3x3, s1, p0) + quanv closed form.
// h2 (B,4,16,16) -> qb padded planes: per (b,ch): stride 80 floats,
// row r (0..6) at 8*(r+1)+c. Pads are zero via the preceding memset.
__global__ __launch_bounds__(256) void k_pre3_quanv(const float* __restrict__ h2,
                                                    const float* __restrict__ w3,
                                                    const float* __restrict__ b3,
                                                    const float* __restrict__ qw,
                                                    float* __restrict__ q) {
    int idx = blockIdx.x * blockDim.x + threadIdx.x;
    if (idx >= B * 4 * 49) return;
    int b = idx / 196;
    int rem = idx % 196;
    int c = rem / 49;
    int pos = rem % 49;
    int oh = pos / 7, ow = pos % 7;
    const float* xin = h2 + b * 1024;
    float xv[4];
#pragma unroll
    for (int dy = 0; dy < 2; ++dy)
#pragma unroll
        for (int dx = 0; dx < 2; ++dx) {
            int oy = 2 * oh + dy, ox = 2 * ow + dx;
            float acc = b3[c];
#pragma unroll
            for (int ci = 0; ci < 4; ++ci)
#pragma unroll
                for (int ky = 0; ky < 3; ++ky)
#pragma unroll
                    for (int kx = 0; kx < 3; ++kx)
                        acc += w3[((c * 4 + ci) * 3 + ky) * 3 + kx] *
                               xin[ci * 256 + (oy + ky) * 16 + (ox + kx)];
            xv[dy * 2 + dx] = acc;
        }
    float prod = 1.f;
    // channel = c*4+w, plane stride 80, sample stride 16*80=1280
    float* qo = q + b * 1280 + c * 320 + 8 * (oh + 1) + ow;
#pragma unroll
    for (int w = 0; w < 4; ++w) {
        float phi = qw[w * 3 + 0];
        float theta = qw[w * 3 + 1];
        float st, ct, sx, cx;
        __sincosf(theta, &st, &ct);
        float sp = __sinf(phi);
        __sincosf(xv[w], &sx, &cx);
        float z = ct * cx - st * sp * sx;
        prod *= z;
        qo[w * 80] = prod;
    }
}

// --------- register-resident helpers (all indices compile-time after unroll)
// Load 12 float4 = 6 padded rows of a plane. h=0: plane+0 (rows -1..4);
// h=1: plane+24 (rows 2..7). Reg row r holds global row (r + 3h - 1).
__device__ __forceinline__ void load_plane12(const float* __restrict__ p, float* dst) {
#pragma unroll
    for (int j = 0; j < 12; ++j) {
        float4 v = reinterpret_cast<const float4*>(p)[j];
        dst[4 * j] = v.x; dst[4 * j + 1] = v.y; dst[4 * j + 2] = v.z; dst[4 * j + 3] = v.w;
    }
}

template <int STRIDE>
__device__ __forceinline__ void load_w9(const float* __restrict__ p, float* w) {
#pragma unroll
    for (int k = 0; k < 9; ++k) w[k] = p[k * STRIDE];
}

// Out local row lr (global 3h+lr), input reg row = lr+ky (zero-pad rows absorb
// edges), input col cc = c-1+kx (cc==7 hits zero col pad; only cc<0 skipped).
__device__ __forceinline__ void conv_rows(const float* pr, const float* w9, float* acc) {
#pragma unroll
    for (int lr = 0; lr < 4; ++lr)
#pragma unroll
        for (int c = 0; c < 7; ++c)
#pragma unroll
            for (int ky = 0; ky < 3; ++ky)
#pragma unroll
                for (int kx = 0; kx < 3; ++kx) {
                    int cc = c - 1 + kx;
                    if (cc < 0) continue;
                    acc[lr * 7 + c] += w9[ky * 3 + kx] * pr[(lr + ky) * 8 + cc];
                }
}

// ---------------- K5+K6 fused: conv1(16->32)+GN+ReLU -> LDS -> conv2(32->64)+GN+ReLU+maxpool.
// 1 block = 1 sample, 128 threads = 2 waves.
// Phase 1 (wave0 only): conv1 (R11-proven math), planes to LDS stride 84
//   (84%32=20, gcd=4 -> <=4-way write conflicts; reads are wave-uniform broadcasts).
//   LDS pads written explicitly before the barrier (rows 0-7 by h0, 64-71 by h1,
//   col7 via float4(...,0)) — covers every index load_plane12 reads (0..71).
// Phase 2 (both waves): conv2 (R11-proven math), wave = co-half.
// in: qb padded [b][16][80] (memset-zeroed pads); out p2 [b][64][9].
__global__ __launch_bounds__(128, 2) void k_conv12_fused(const float* __restrict__ qb,
                                                         const float* __restrict__ tw1,
                                                         const float* __restrict__ b1,
                                                         const float* __restrict__ gw1,
                                                         const float* __restrict__ gb1,
                                                         const float* __restrict__ tw2,
                                                         const float* __restrict__ b2c,
                                                         const float* __restrict__ gw2,
                                                         const float* __restrict__ gb2,
                                                         float* __restrict__ out) {
    __shared__ float s_g1[32 * 84];   // 10752 B
    int b = blockIdx.x;
    int wave = threadIdx.x >> 6;
    int lane = threadIdx.x & 63;
    int col = lane & 31;
    int h = lane >> 5;

    if (wave == 0) {
        // ---- conv1: co = col ----
        const float* pin = qb + b * 1280 + 24 * h;
        float acc[28];
        float bco = b1[col];
#pragma unroll
        for (int p = 0; p < 28; ++p) acc[p] = bco;
        float pa[48], pb[48], wa[9], wb[9];
        load_plane12(pin, pa);
        load_w9<32>(tw1 + col, wa);
#pragma unroll
        for (int ci = 0; ci < 16; ci += 2) {
            load_plane12(pin + (ci + 1) * 80, pb);
            load_w9<32>(tw1 + (ci + 1) * 288 + col, wb);
            conv_rows(pa, wa, acc);
            if (ci + 2 < 16) {
                load_plane12(pin + (ci + 2) * 80, pa);
                load_w9<32>(tw1 + (ci + 2) * 288 + col, wa);
            }
            conv_rows(pb, wb, acc);
        }
        // GN: 4 adjacent co x 49 pos. half1's lr0 (row 3) duplicates half0's lr3.
        float sum = 0.f, ssq = 0.f;
#pragma unroll
        for (int lr = 0; lr < 4; ++lr) {
            float rs_ = 0.f, rq_ = 0.f;
#pragma unroll
            for (int c = 0; c < 7; ++c) { float v = acc[lr * 7 + c]; rs_ += v; rq_ += v * v; }
            if (lr > 0 || h == 0) { sum += rs_; ssq += rq_; }
        }
        sum += __shfl_xor(sum, 1);  ssq += __shfl_xor(ssq, 1);
        sum += __shfl_xor(sum, 2);  ssq += __shfl_xor(ssq, 2);
        sum += __shfl_xor(sum, 32); ssq += __shfl_xor(ssq, 32);
        float mu = sum * (1.f / 196.f);
        float var = ssq * (1.f / 196.f) - mu * mu;
        float rs = rsqrtf(var + 1e-5f);
        float ga = gw1[col] * rs;
        float be = gb1[col] - mu * ga;
        float* o = s_g1 + col * 84;
        // pad zeros: h0 -> top rows idx 0-7; h1 -> bottom idx 64-71
        if (h == 0) {
            *reinterpret_cast<float4*>(o)     = make_float4(0.f, 0.f, 0.f, 0.f);
            *reinterpret_cast<float4*>(o + 4) = make_float4(0.f, 0.f, 0.f, 0.f);
        } else {
            *reinterpret_cast<float4*>(o + 64) = make_float4(0.f, 0.f, 0.f, 0.f);
            *reinterpret_cast<float4*>(o + 68) = make_float4(0.f, 0.f, 0.f, 0.f);
        }
#pragma unroll
        for (int lr = 0; lr < 4; ++lr) {
            if (h == 1 && lr == 0) continue;
            int row = lr + 3 * h;
            float r0 = fmaxf(acc[lr * 7 + 0] * ga + be, 0.f);
            float r1 = fmaxf(acc[lr * 7 + 1] * ga + be, 0.f);
            float r2 = fmaxf(acc[lr * 7 + 2] * ga + be, 0.f);
            float r3 = fmaxf(acc[lr * 7 + 3] * ga + be, 0.f);
            float r4 = fmaxf(acc[lr * 7 + 4] * ga + be, 0.f);
            float r5 = fmaxf(acc[lr * 7 + 5] * ga + be, 0.f);
            float r6 = fmaxf(acc[lr * 7 + 6] * ga + be, 0.f);
            float* rowp = o + 8 * (row + 1);
            *reinterpret_cast<float4*>(rowp)     = make_float4(r0, r1, r2, r3);
            *reinterpret_cast<float4*>(rowp + 4) = make_float4(r4, r5, r6, 0.f);  // col7 = 0 pad
        }
    }
    __syncthreads();

    // ---- conv2: co = wave*32 + col ----
    int co = wave * 32 + col;
    const float* pin = s_g1 + 24 * h;
    float acc[28];
    float bco = b2c[co];
#pragma unroll
    for (int p = 0; p < 28; ++p) acc[p] = bco;
    float pa[48], pb[48], wa[9], wb[9];
    load_plane12(pin, pa);
    load_w9<64>(tw2 + co, wa);
#pragma unroll
    for (int ci = 0; ci < 32; ci += 2) {
        load_plane12(pin + (ci + 1) * 84, pb);
        load_w9<64>(tw2 + (ci + 1) * 576 + co, wb);
        conv_rows(pa, wa, acc);
        if (ci + 2 < 32) {
            load_plane12(pin + (ci + 2) * 84, pa);
            load_w9<64>(tw2 + (ci + 2) * 576 + co, wa);
        }
        conv_rows(pb, wb, acc);
    }
    // GN: 8 adjacent co x 49 pos (groups 4*wave..4*wave+3, fully in-wave)
    float sum = 0.f, ssq = 0.f;
#pragma unroll
    for (int lr = 0; lr < 4; ++lr) {
        float rs_ = 0.f, rq_ = 0.f;
#pragma unroll
        for (int c = 0; c < 7; ++c) { float v = acc[lr * 7 + c]; rs_ += v; rq_ += v * v; }
        if (lr > 0 || h == 0) { sum += rs_; ssq += rq_; }
    }
    sum += __shfl_xor(sum, 1);  ssq += __shfl_xor(ssq, 1);
    sum += __shfl_xor(sum, 2);  ssq += __shfl_xor(ssq, 2);
    sum += __shfl_xor(sum, 4);  ssq += __shfl_xor(ssq, 4);
    sum += __shfl_xor(sum, 32); ssq += __shfl_xor(ssq, 32);
    float mu = sum * (1.f / 392.f);
    float var = ssq * (1.f / 392.f) - mu * mu;
    float rs = rsqrtf(var + 1e-5f);
    float ga = gw2[co] * rs;
    float be = gb2[co] - mu * ga;
#pragma unroll
    for (int p = 0; p < 28; ++p) acc[p] = fmaxf(acc[p] * ga + be, 0.f);
    // maxpool 2x2 on rows/cols 0..5. half0: py 0,1 (lr 0-3); half1: py 2 (lr 1,2 = rows 4,5)
    float* o = out + b * 576 + co * 9;
    if (h == 0) {
#pragma unroll
        for (int py = 0; py < 2; ++py)
#pragma unroll
            for (int px = 0; px < 3; ++px) {
                int p0 = (2 * py) * 7 + 2 * px;
                float m = fmaxf(fmaxf(acc[p0], acc[p0 + 1]), fmaxf(acc[p0 + 7], acc[p0 + 8]));
                o[py * 3 + px] = m;
            }
    } else {
#pragma unroll
        for (int px = 0; px < 3; ++px) {
            int p0 = 7 + 2 * px;   // lr 1 = global row 4
            float m = fmaxf(fmaxf(acc[p0], acc[p0 + 1]), fmaxf(acc[p0 + 7], acc[p0 + 8]));
            o[6 + px] = m;
        }
    }
}

// ---------------- K7: fc1 576->128 + ReLU + fc2 128->10. 8 samples/block, 128 threads.
__global__ __launch_bounds__(128) void k_fc(const float* __restrict__ p2,
                                            const float* __restrict__ w1,
                                            const float* __restrict__ b1,
                                            const float* __restrict__ w2,
                                            const float* __restrict__ b2,
                                            float* __restrict__ out) {
    __shared__ float s_p[8 * 576];
    __shared__ float s_f[8][132];   // pad 132: avoid 8-way stride-128 bank conflict in fc2
    int b0 = blockIdx.x * 8, tid = threadIdx.x;
    for (int i = tid; i < 8 * 576; i += 128) s_p[i] = p2[b0 * 576 + i];
    __syncthreads();
    {
        float acc[8];
        float bv = b1[tid];
#pragma unroll
        for (int s = 0; s < 8; ++s) acc[s] = bv;
        const float4* wr = reinterpret_cast<const float4*>(w1 + tid * 576);
        const float4* sp = reinterpret_cast<const float4*>(s_p);
        for (int j = 0; j < 144; ++j) {
            float4 a = wr[j];
#pragma unroll
            for (int s = 0; s < 8; ++s) {
                float4 c = sp[s * 144 + j];
                acc[s] += a.x * c.x + a.y * c.y + a.z * c.z + a.w * c.w;
            }
        }
#pragma unroll
        for (int s = 0; s < 8; ++s) s_f[s][tid] = fmaxf(acc[s], 0.f);
    }
    __syncthreads();
    if (tid < 80) {
        int s = tid / 10, o = tid % 10;
        float acc = b2[o];
        const float* wr = w2 + o * 128;
#pragma unroll 8
        for (int j = 0; j < 128; ++j) acc += wr[j] * s_f[s][j];
        out[(b0 + s) * 10 + o] = acc;
    }
}

extern "C" void kernel_launch(void* const* d_in, const int* in_sizes, int n_in,
                              void* d_out, int out_size, void* d_ws, size_t ws_size,
                              hipStream_t stream) {
    const float* x       = (const float*)d_in[0];
    const float* pre_w1  = (const float*)d_in[1];
    const float* pre_b1  = (const float*)d_in[2];
    const float* pre_w2  = (const float*)d_in[3];
    const float* pre_b2  = (const float*)d_in[4];
    const float* pre_w3  = (const float*)d_in[5];
    const float* pre_b3  = (const float*)d_in[6];
    const float* qweights= (const float*)d_in[7];
    const float* conv1_w = (const float*)d_in[8];
    const float* conv1_b = (const float*)d_in[9];
    const float* gn1_w   = (const float*)d_in[10];
    const float* gn1_b   = (const float*)d_in[11];
    const float* conv2_w = (const float*)d_in[12];
    const float* conv2_b = (const float*)d_in[13];
    const float* gn2_w   = (const float*)d_in[14];
    const float* gn2_b   = (const float*)d_in[15];
    const float* fc1_w   = (const float*)d_in[16];
    const float* fc1_b   = (const float*)d_in[17];
    const float* fc2_w   = (const float*)d_in[18];
    const float* fc2_b   = (const float*)d_in[19];
    float* out = (float*)d_out;

    // workspace (floats), liveness-based reuse:
    //  h1 [0, 4194304)            : K1->K2
    //  qb [0, 1310720)            : K3q->K56 (after h1 dead; memset-zeroed pads)
    //  h2 [4194304, 5242880)      : K2->K3q
    //  p2 [4194304, 4784128)      : K56->K7 (reuses h2 region after last read)
    //  tw [6045696, +23040)       : K1->K56
    float* ws = (float*)d_ws;
    float* h1 = ws;
    float* qb = ws;
    float* h2 = ws + 4194304;
    float* p2 = ws + 4194304;
    float* tw1 = ws + 6045696;
    float* tw2 = ws + 6045696 + 4608;

    k_pre1<<<4168, 256, 0, stream>>>(x, pre_w1, pre_b1, h1, conv1_w, conv2_w, tw1, tw2);
    k_pre2<<<(B * 16 * 16 + 255) / 256, 256, 0, stream>>>(h1, pre_w2, pre_b2, h2);
    // zero qb (pads must be 0; h1 is dead after k_pre2)
    hipMemsetAsync(ws, 0, 1310720 * sizeof(float), stream);
    k_pre3_quanv<<<(B * 4 * 49 + 255) / 256, 256, 0, stream>>>(h2, pre_w3, pre_b3, qweights, qb);
    k_conv12_fused<<<B, 128, 0, stream>>>(qb, tw1, conv1_b, gn1_w, gn1_b,
                                          tw2, conv2_b, gn2_w, gn2_b, p2);
    k_fc<<<(B / 8), 128, 0, stream>>>(p2, fc1_w, fc1_b, fc2_w, fc2_b, out);
}